// Round 2
// baseline (3390.792 us; speedup 1.0000x reference)
//
#include <hip/hip_runtime.h>

// ---------------------------------------------------------------------------
// SensorClassifierDualEncoder on MI355X (gfx950) — R6 (resubmit; prior run
// died to container-infra failure, no counters returned)
// B=32768, S=5, D=512, E=256, H=4 (DH=64), F=2048, L=2, C=5. N_TOK = B*S.
//
// R6: ffn_fused was latency-bound (Occupancy 24%, MfmaUtil 17%, HBM 6%:
// nothing saturated). Cause: 105KB LDS -> 1 block/CU -> 2 waves/SIMD; 32
// barriers/block stall the whole CU; post-barrier W-fragment loads (~300cy
// L2) feed MFMA directly. Changes:
//  * 64 tokens / 256 threads (4 waves) per block -> LDS 53.8KB -> 3
//    blocks/CU (12 waves/CU). Barriers of one block hide under the other
//    two blocks. W L2 traffic per block halves.
//  * Cross-barrier W prefetch: W2[k=0] frags issued before the smid-write
//    barrier pair; next chunk's W1[k=0] frags issued at top of P2.
//  * s_setprio(1) around MFMA clusters (T5: pays once wave roles diverge).
// ---------------------------------------------------------------------------

#define N_TOK 163840
#define NBATCH 32768

typedef __attribute__((ext_vector_type(8))) short bfrag;   // 8 bf16 (4 VGPRs)
typedef __attribute__((ext_vector_type(4))) float f32x4;

__device__ __forceinline__ float bf2f(ushort u) {
  return __builtin_bit_cast(float, (uint)u << 16);
}
__device__ __forceinline__ ushort f2bf(float f) {
  uint u = __builtin_bit_cast(uint, f);
  return (ushort)((u + 0x7FFFu + ((u >> 16) & 1u)) >> 16);   // RNE
}

// --------------------------- fp32 -> bf16 cast -----------------------------
__global__ __launch_bounds__(256) void cvt_kernel(const float* __restrict__ in,
                                                  ushort* __restrict__ out, int n4) {
  int i = blockIdx.x * 256 + threadIdx.x;
  if (i >= n4) return;
  float4 v = ((const float4*)in)[i];
  ushort4 o;
  o.x = f2bf(v.x); o.y = f2bf(v.y); o.z = f2bf(v.z); o.w = f2bf(v.w);
  ((ushort4*)out)[i] = o;
}

// --------------------------- pipelined MFMA GEMM ---------------------------
// C[M,O] = A[M,K] * W[O,K]^T + bias. block 256 = 4 waves, tile 128x128.
// LDS [128][32], XOR-chunk swizzle; reg-prefetch pipeline.
enum { EPI_F32 = 0, EPI_F32_RELU = 1, EPI_BF16 = 2, EPI_BF16_RELU = 3, EPI_SELECT = 4 };

template <int EPI>
__global__ __launch_bounds__(256) void gemm_bt(const ushort* __restrict__ A,
                                               const ushort* __restrict__ W,
                                               const float* __restrict__ bias,
                                               void* __restrict__ outp,
                                               int M, int K, int O,
                                               const float* __restrict__ gbuf,
                                               const int* __restrict__ stype,
                                               ushort* __restrict__ h16out) {
  __shared__ ushort As[128][32];
  __shared__ ushort Bs[128][32];
  const int tid = threadIdx.x;
  const int wave = tid >> 6, lane = tid & 63;
  const int bm = blockIdx.y, bn = blockIdx.x;
  const int wm = (wave & 1) << 6, wn = (wave >> 1) << 6;
  const int srow = tid >> 2;                               // 0..63 (+64)
  const int sq   = tid & 3;                                // k-chunk 0..3
  const int sc   = ((sq ^ ((srow >> 2) & 3))) << 3;        // swizzled chunk
  const int scol = sq << 3;                                // global k offset

  const ushort* Abase = A + (size_t)(bm * 128 + srow) * K + scol;
  const ushort* Wbase = W + (size_t)(bn * 128 + srow) * K + scol;

  f32x4 acc[4][4];
#pragma unroll
  for (int i = 0; i < 4; i++)
#pragma unroll
    for (int j = 0; j < 4; j++) acc[i][j] = {0.f, 0.f, 0.f, 0.f};

  const int fr = lane & 15;                                // fragment row
  const int fq = lane >> 4;                                // k-quad
  const int rc = (fq ^ ((fr >> 2) & 3)) << 3;              // swizzled read chunk

  uint4 a0 = *(const uint4*)(Abase);
  uint4 a1 = *(const uint4*)(Abase + (size_t)64 * K);
  uint4 b0 = *(const uint4*)(Wbase);
  uint4 b1 = *(const uint4*)(Wbase + (size_t)64 * K);

  for (int k0 = 0; k0 < K; k0 += 32) {
    *(uint4*)&As[srow][sc]      = a0;
    *(uint4*)&As[srow + 64][sc] = a1;
    *(uint4*)&Bs[srow][sc]      = b0;
    *(uint4*)&Bs[srow + 64][sc] = b1;
    __syncthreads();
    if (k0 + 32 < K) {                  // prefetch next k-step (hidden by MFMA)
      a0 = *(const uint4*)(Abase + k0 + 32);
      a1 = *(const uint4*)(Abase + k0 + 32 + (size_t)64 * K);
      b0 = *(const uint4*)(Wbase + k0 + 32);
      b1 = *(const uint4*)(Wbase + k0 + 32 + (size_t)64 * K);
    }
    bfrag af[4], bf_[4];
#pragma unroll
    for (int i = 0; i < 4; i++) af[i] = *(const bfrag*)&As[wm + i * 16 + fr][rc];
#pragma unroll
    for (int j = 0; j < 4; j++) bf_[j] = *(const bfrag*)&Bs[wn + j * 16 + fr][rc];
#pragma unroll
    for (int i = 0; i < 4; i++)
#pragma unroll
      for (int j = 0; j < 4; j++)
        acc[i][j] = __builtin_amdgcn_mfma_f32_16x16x32_bf16(af[i], bf_[j], acc[i][j], 0, 0, 0);
    __syncthreads();
  }

  // epilogue: C/D layout col=lane&15, row=(lane>>4)*4+r
  const int cr = fq << 2;
  const int cc = fr;
#pragma unroll
  for (int j = 0; j < 4; j++) {
    const int col = bn * 128 + wn + j * 16 + cc;
    const float bv = bias[col];
#pragma unroll
    for (int i = 0; i < 4; i++) {
      const int row = bm * 128 + wm + i * 16 + cr;
#pragma unroll
      for (int r = 0; r < 4; r++) {
        float v = acc[i][j][r] + bv;
        const size_t idx = (size_t)(row + r) * O + col;
        if (EPI != EPI_F32 && EPI != EPI_BF16) v = fmaxf(v, 0.f);
        if (EPI == EPI_SELECT) {
          if (stype[row + r] == 0) v = gbuf[idx];   // gps branch precomputed
          ((float*)outp)[idx] = v;
          h16out[idx] = f2bf(v);
        } else if (EPI == EPI_F32 || EPI == EPI_F32_RELU) {
          ((float*)outp)[idx] = v;
        } else {
          ((ushort*)outp)[idx] = f2bf(v);
        }
      }
    }
  }
}

// ---------- pipelined GEMM (O=256) + residual + LayerNorm ------------------
// tile 128 rows x 256 cols, 512 thr = 8 waves, wave 64x64. Swizzled LDS.
__global__ __launch_bounds__(512) void gemm_lnres(const ushort* __restrict__ A,
                                                  const ushort* __restrict__ W,
                                                  const float* __restrict__ bias,
                                                  float* __restrict__ h32,
                                                  ushort* __restrict__ h16,
                                                  const float* __restrict__ g,
                                                  const float* __restrict__ b,
                                                  int K) {
  __shared__ ushort As[128][32];
  __shared__ ushort Bs[256][32];
  __shared__ float2 s_part[128][4];
  __shared__ float2 s_mr[128];
  const int tid = threadIdx.x;
  const int wave = tid >> 6, lane = tid & 63;
  const int bm = blockIdx.x;
  const int wm = (wave & 1) << 6, wn = (wave >> 1) << 6;

  const int srow = tid >> 2;                               // 0..127
  const int sq   = tid & 3;
  const int sc   = ((sq ^ ((srow >> 2) & 3))) << 3;
  const int scol = sq << 3;
  const ushort* Ag = A + (size_t)(bm * 128 + srow) * K + scol;
  const ushort* Wg = W + (size_t)srow * K + scol;

  f32x4 acc[4][4];
#pragma unroll
  for (int i = 0; i < 4; i++)
#pragma unroll
    for (int j = 0; j < 4; j++) acc[i][j] = {0.f, 0.f, 0.f, 0.f};

  const int fr = lane & 15;
  const int fq = lane >> 4;
  const int rc = (fq ^ ((fr >> 2) & 3)) << 3;

  uint4 a0 = *(const uint4*)(Ag);
  uint4 b0 = *(const uint4*)(Wg);
  uint4 b1 = *(const uint4*)(Wg + (size_t)128 * K);

  for (int k0 = 0; k0 < K; k0 += 32) {
    *(uint4*)&As[srow][sc]       = a0;
    *(uint4*)&Bs[srow][sc]       = b0;
    *(uint4*)&Bs[srow + 128][sc] = b1;
    __syncthreads();
    if (k0 + 32 < K) {
      a0 = *(const uint4*)(Ag + k0 + 32);
      b0 = *(const uint4*)(Wg + k0 + 32);
      b1 = *(const uint4*)(Wg + k0 + 32 + (size_t)128 * K);
    }
    bfrag af[4], bf_[4];
#pragma unroll
    for (int i = 0; i < 4; i++) af[i] = *(const bfrag*)&As[wm + i * 16 + fr][rc];
#pragma unroll
    for (int j = 0; j < 4; j++) bf_[j] = *(const bfrag*)&Bs[wn + j * 16 + fr][rc];
#pragma unroll
    for (int i = 0; i < 4; i++)
#pragma unroll
      for (int j = 0; j < 4; j++)
        acc[i][j] = __builtin_amdgcn_mfma_f32_16x16x32_bf16(af[i], bf_[j], acc[i][j], 0, 0, 0);
    __syncthreads();
  }

  const int cr = fq << 2;
  const int cc = fr;
#pragma unroll
  for (int i = 0; i < 4; i++) {
#pragma unroll
    for (int r = 0; r < 4; r++) {
      const int row = wm + i * 16 + cr + r;
      const size_t grow = (size_t)(bm * 128 + row) * 256;
      float s = 0.f, sq2 = 0.f;
#pragma unroll
      for (int j = 0; j < 4; j++) {
        const int col = wn + j * 16 + cc;
        float u = acc[i][j][r] + bias[col] + h32[grow + col];
        acc[i][j][r] = u;
        s += u; sq2 += u * u;
      }
#pragma unroll
      for (int o = 1; o < 16; o <<= 1) { s += __shfl_xor(s, o); sq2 += __shfl_xor(sq2, o); }
      if ((lane & 15) == 0) s_part[row][wave >> 1] = {s, sq2};
    }
  }
  __syncthreads();
  if (tid < 128) {
    float2 p0 = s_part[tid][0], p1 = s_part[tid][1], p2 = s_part[tid][2], p3 = s_part[tid][3];
    float S = p0.x + p1.x + p2.x + p3.x;
    float SQ = p0.y + p1.y + p2.y + p3.y;
    float mean = S * 0.00390625f;
    float var = SQ * 0.00390625f - mean * mean;
    s_mr[tid] = {mean, rsqrtf(var + 1e-5f)};
  }
  __syncthreads();
#pragma unroll
  for (int i = 0; i < 4; i++) {
#pragma unroll
    for (int r = 0; r < 4; r++) {
      const int row = wm + i * 16 + cr + r;
      const float2 mr = s_mr[row];
      const size_t grow = (size_t)(bm * 128 + row) * 256;
#pragma unroll
      for (int j = 0; j < 4; j++) {
        const int col = wn + j * 16 + cc;
        float y = (acc[i][j][r] - mr.x) * mr.y * g[col] + b[col];
        h32[grow + col] = y;
        h16[grow + col] = f2bf(y);
      }
    }
  }
}

// --------------------- fused FFN: ff1+ReLU+ff2+res+LN ----------------------
// R6: block = 256 thr (4 waves), 64 tokens. LDS 53.8KB -> 3 blocks/CU.
// h in LDS once; 16 chunks of 128 mid-cols: P1 (K=256, h x W1^T -> smid),
// P2 (K=128, smid x W2^T -> persistent acc2). W1/W2 fragments direct from
// global (L2-hot); W2[k=0] prefetched before the barrier pair, next chunk's
// W1[k=0] prefetched at top of P2 (compiler cannot hoist loads over
// s_barrier). setprio(1) around MFMA clusters.
__global__ __launch_bounds__(256, 3) void ffn_fused(const ushort* __restrict__ h16in,
                                                    const ushort* __restrict__ W1,
                                                    const float* __restrict__ b1,
                                                    const ushort* __restrict__ W2,
                                                    const float* __restrict__ b2,
                                                    float* __restrict__ h32,
                                                    ushort* __restrict__ h16out,
                                                    const float* __restrict__ g,
                                                    const float* __restrict__ bb) {
  __shared__ ushort sh[64][264];      // h: stride 132 dw == 4 mod 32 (2-way max)
  __shared__ ushort smid[64][136];    // mid chunk: stride 68 dw == 4 mod 32
  __shared__ float2 s_part[64][4];
  __shared__ float2 s_mr[64];
  const int tid = threadIdx.x;
  const int wave = tid >> 6, lane = tid & 63;
  const size_t tok0 = (size_t)blockIdx.x * 64;

  // stage h: 4 threads/row, 64 ushorts each
  {
    const int r = tid >> 2, c0 = (tid & 3) << 6;
    const ushort* src = h16in + (tok0 + r) * 256 + c0;
#pragma unroll
    for (int u = 0; u < 8; u++)
      *(uint4*)&sh[r][c0 + u * 8] = *(const uint4*)(src + u * 8);
  }

  const int fr = lane & 15;           // fragment row
  const int fq = lane >> 4;           // k-quad
  const int cr = fq << 2;             // C-layout row offset
  const int cc = fr;                  // C-layout col
  const int mq = wave << 5;           // P1 mid-col base (32 per wave)
  const int oq = wave << 6;           // P2 out-col base (64 per wave)

  // per-lane W base pointers
  const ushort* w1p = W1 + (size_t)(mq + fr) * 256 + fq * 8;   // +j*4096 +c*32768 +k*32
  const ushort* w2p = W2 + (size_t)(oq + fr) * 2048 + fq * 8;  // +j*32768 +c*128 +k*32

  f32x4 acc2[4][4];
#pragma unroll
  for (int i = 0; i < 4; i++)
#pragma unroll
    for (int j = 0; j < 4; j++) acc2[i][j] = {0.f, 0.f, 0.f, 0.f};

  bfrag nb1[2];                       // prefetched W1 frags (chunk c, k=0)
  nb1[0] = *(const bfrag*)(w1p);
  nb1[1] = *(const bfrag*)(w1p + 16 * 256);

  __syncthreads();                    // sh staged

  for (int c = 0; c < 16; c++) {
    const size_t c1 = (size_t)c * 32768;    // W1 chunk offset (128 rows * 256)
    // ---- P1: mid = relu(h * W1[c]^T + b1) ; 64 tok x 32 mid per wave ----
    f32x4 acc1[4][2];
#pragma unroll
    for (int i = 0; i < 4; i++)
#pragma unroll
      for (int j = 0; j < 2; j++) acc1[i][j] = {0.f, 0.f, 0.f, 0.f};
#pragma unroll
    for (int k = 0; k < 8; k++) {
      bfrag b1f[2];
      if (k == 0) { b1f[0] = nb1[0]; b1f[1] = nb1[1]; }
      else {
        b1f[0] = *(const bfrag*)(w1p + c1 + k * 32);
        b1f[1] = *(const bfrag*)(w1p + c1 + 16 * 256 + k * 32);
      }
      const int ko = k * 32 + fq * 8;
      bfrag af[4];
#pragma unroll
      for (int i = 0; i < 4; i++) af[i] = *(const bfrag*)&sh[i * 16 + fr][ko];
      __builtin_amdgcn_s_setprio(1);
#pragma unroll
      for (int i = 0; i < 4; i++)
#pragma unroll
        for (int j = 0; j < 2; j++)
          acc1[i][j] = __builtin_amdgcn_mfma_f32_16x16x32_bf16(af[i], b1f[j], acc1[i][j], 0, 0, 0);
      __builtin_amdgcn_s_setprio(0);
    }
    // prefetch W2 (chunk c, k=0) before the barrier pair — hides L2 latency
    bfrag nb2[4];
#pragma unroll
    for (int j = 0; j < 4; j++)
      nb2[j] = *(const bfrag*)(w2p + (size_t)j * 32768 + c * 128);

    __syncthreads();   // prev P2 done reading smid
#pragma unroll
    for (int j = 0; j < 2; j++) {
      const float bv = b1[c * 128 + mq + j * 16 + cc];
#pragma unroll
      for (int i = 0; i < 4; i++)
#pragma unroll
        for (int r = 0; r < 4; r++) {
          float v = fmaxf(acc1[i][j][r] + bv, 0.f);
          smid[i * 16 + cr + r][mq + j * 16 + cc] = f2bf(v);
        }
    }
    __syncthreads();   // smid ready
    // ---- P2: acc2 += mid * W2[:,c]^T ; 64 tok x 64 out per wave ----
#pragma unroll
    for (int k = 0; k < 4; k++) {
      bfrag b2f[4];
      if (k == 0) {
        b2f[0] = nb2[0]; b2f[1] = nb2[1]; b2f[2] = nb2[2]; b2f[3] = nb2[3];
        // prefetch next chunk's W1 k=0 (no barrier between here and next P1)
        const size_t cn = (size_t)((c + 1) & 15) * 32768;
        nb1[0] = *(const bfrag*)(w1p + cn);
        nb1[1] = *(const bfrag*)(w1p + cn + 16 * 256);
      } else {
#pragma unroll
        for (int j = 0; j < 4; j++)
          b2f[j] = *(const bfrag*)(w2p + (size_t)j * 32768 + c * 128 + k * 32);
      }
      const int ko = k * 32 + fq * 8;
      bfrag af[4];
#pragma unroll
      for (int i = 0; i < 4; i++) af[i] = *(const bfrag*)&smid[i * 16 + fr][ko];
      __builtin_amdgcn_s_setprio(1);
#pragma unroll
      for (int i = 0; i < 4; i++)
#pragma unroll
        for (int j = 0; j < 4; j++)
          acc2[i][j] = __builtin_amdgcn_mfma_f32_16x16x32_bf16(af[i], b2f[j], acc2[i][j], 0, 0, 0);
      __builtin_amdgcn_s_setprio(0);
    }
  }

  // ---- epilogue: u = acc2 + b2 + h32 ; LN -> h32, h16 ----
#pragma unroll
  for (int i = 0; i < 4; i++) {
#pragma unroll
    for (int r = 0; r < 4; r++) {
      const int row = i * 16 + cr + r;
      const size_t grow = (tok0 + row) * 256;
      float s = 0.f, sq2 = 0.f;
#pragma unroll
      for (int j = 0; j < 4; j++) {
        const int col = oq + j * 16 + cc;
        float u = acc2[i][j][r] + b2[col] + h32[grow + col];
        acc2[i][j][r] = u;
        s += u; sq2 += u * u;
      }
#pragma unroll
      for (int o = 1; o < 16; o <<= 1) { s += __shfl_xor(s, o); sq2 += __shfl_xor(sq2, o); }
      if ((lane & 15) == 0) s_part[row][wave] = {s, sq2};
    }
  }
  __syncthreads();
  if (tid < 64) {
    float2 p0 = s_part[tid][0], p1 = s_part[tid][1], p2 = s_part[tid][2], p3 = s_part[tid][3];
    float S = p0.x + p1.x + p2.x + p3.x;
    float SQ = p0.y + p1.y + p2.y + p3.y;
    float mean = S * 0.00390625f;
    float var = SQ * 0.00390625f - mean * mean;
    s_mr[tid] = {mean, rsqrtf(var + 1e-5f)};
  }
  __syncthreads();
#pragma unroll
  for (int i = 0; i < 4; i++) {
#pragma unroll
    for (int r = 0; r < 4; r++) {
      const int row = i * 16 + cr + r;
      const float2 mr = s_mr[row];
      const size_t grow = (tok0 + row) * 256;
#pragma unroll
      for (int j = 0; j < 4; j++) {
        const int col = oq + j * 16 + cc;
        float y = (acc2[i][j][r] - mr.x) * mr.y * g[col] + bb[col];
        h32[grow + col] = y;
        h16out[grow + col] = f2bf(y);
      }
    }
  }
}

// --------------------------- attention (S=5) -------------------------------
__global__ __launch_bounds__(256) void attn_kernel(const ushort* __restrict__ qkv,
                                                   ushort* __restrict__ o16) {
  __shared__ ushort s_qkv[8 * 5 * 768];   // 61440 B
  __shared__ float s_att[8 * 4 * 25];
  const int tid = threadIdx.x;
  const size_t gbase = (size_t)blockIdx.x * (8 * 5 * 768);
#pragma unroll
  for (int t = 0; t < 15; t++) {
    int i = tid + t * 256;
    *(uint4*)&s_qkv[i * 8] = *(const uint4*)(qkv + gbase + (size_t)i * 8);
  }
  __syncthreads();
  for (int idx = tid; idx < 800; idx += 256) {
    int b = idx / 100, r = idx - b * 100;
    int h = r / 25, ij = r - h * 25;
    int i = ij / 5, j = ij - i * 5;
    const ushort* qp = &s_qkv[(b * 5 + i) * 768 + h * 64];
    const ushort* kp = &s_qkv[(b * 5 + j) * 768 + 256 + h * 64];
    float s = 0.f;
#pragma unroll
    for (int d = 0; d < 64; d += 2) {
      uint qw = *(const uint*)&qp[d];
      uint kw = *(const uint*)&kp[d];
      s += bf2f((ushort)(qw & 0xffffu)) * bf2f((ushort)(kw & 0xffffu));
      s += bf2f((ushort)(qw >> 16)) * bf2f((ushort)(kw >> 16));
    }
    s_att[idx] = s * 0.125f;   // 1/sqrt(64)
  }
  __syncthreads();
  if (tid < 160) {
    float* sp = &s_att[tid * 5];
    float m = fmaxf(fmaxf(fmaxf(sp[0], sp[1]), fmaxf(sp[2], sp[3])), sp[4]);
    float e0 = __expf(sp[0] - m), e1 = __expf(sp[1] - m), e2 = __expf(sp[2] - m);
    float e3 = __expf(sp[3] - m), e4 = __expf(sp[4] - m);
    float inv = 1.f / (e0 + e1 + e2 + e3 + e4);
    sp[0] = e0 * inv; sp[1] = e1 * inv; sp[2] = e2 * inv; sp[3] = e3 * inv; sp[4] = e4 * inv;
  }
  __syncthreads();
  const size_t obase = (size_t)blockIdx.x * (8 * 5 * 256);
#pragma unroll
  for (int t = 0; t < 40; t++) {
    int idx = t * 256 + tid;
    int d = idx & 63;
    int rest = idx >> 6;
    int h = rest & 3; rest >>= 2;
    int i = rest % 5, b = rest / 5;
    const float* ap = &s_att[(b * 4 + h) * 25 + i * 5];
    const ushort* vp = &s_qkv[(b * 5) * 768 + 512 + h * 64 + d];
    float o = 0.f;
#pragma unroll
    for (int j = 0; j < 5; j++) o += ap[j] * bf2f(vp[j * 768]);
    o16[obase + (size_t)((b * 5 + i) * 256 + h * 64 + d)] = f2bf(o);
  }
}

// --------------------------- head: fc2 + out (fp32) ------------------------
__global__ __launch_bounds__(256) void head2_kernel(const float* __restrict__ z1,
                                                    const float* __restrict__ fc2w,
                                                    const float* __restrict__ fc2b,
                                                    const float* __restrict__ outw,
                                                    const float* __restrict__ outb,
                                                    float* __restrict__ out) {
  __shared__ float s_z2[4][64];
  const int wave = threadIdx.x >> 6, lane = threadIdx.x & 63;
  const int b = blockIdx.x * 4 + wave;
  const float* z = z1 + (size_t)b * 128;
  float acc = fc2b[lane];
#pragma unroll 8
  for (int k = 0; k < 128; k++) acc += z[k] * fc2w[lane * 128 + k];
  s_z2[wave][lane] = acc;
  __syncthreads();
  if (lane < 5) {
    const float* zz = s_z2[wave];
    float o = outb[lane];
#pragma unroll 8
    for (int k = 0; k < 64; k++) o += zz[k] * outw[lane * 64 + k];
    out[(size_t)b * 5 + lane] = o;
  }
}

// ---------------------------------------------------------------------------
extern "C" void kernel_launch(void* const* d_in, const int* in_sizes, int n_in,
                              void* d_out, int out_size, void* d_ws, size_t ws_size,
                              hipStream_t stream) {
  const float* x       = (const float*)d_in[0];
  const int*   stype   = (const int*)d_in[1];
  const float* gps_w   = (const float*)d_in[2];
  const float* gps_b   = (const float*)d_in[3];
  const float* ang_w   = (const float*)d_in[4];
  const float* ang_b   = (const float*)d_in[5];
  const float* qkv_w   = (const float*)d_in[6];
  const float* qkv_b   = (const float*)d_in[7];
  const float* attn_ow = (const float*)d_in[8];
  const float* attn_ob = (const float*)d_in[9];
  const float* ln1_g   = (const float*)d_in[10];
  const float* ln1_b   = (const float*)d_in[11];
  const float* ff1_w   = (const float*)d_in[12];
  const float* ff1_b   = (const float*)d_in[13];
  const float* ff2_w   = (const float*)d_in[14];
  const float* ff2_b   = (const float*)d_in[15];
  const float* ln2_g   = (const float*)d_in[16];
  const float* ln2_b   = (const float*)d_in[17];
  const float* fc1_w   = (const float*)d_in[18];
  const float* fc1_b   = (const float*)d_in[19];
  const float* fc2_w   = (const float*)d_in[20];
  const float* fc2_b   = (const float*)d_in[21];
  const float* out_w   = (const float*)d_in[22];
  const float* out_b   = (const float*)d_in[23];

  char* ws = (char*)d_ws;
  const size_t NEED = 763363328ull;
  if (ws_size < NEED) return;

  // bf16 weight pool
  ushort* w_gps  = (ushort*)ws;                 // 131072
  ushort* w_ang  = w_gps + 131072;
  ushort* w_qkv  = w_ang + 131072;              // 393216 (L*768*256)
  ushort* w_attn = w_qkv + 393216;              // 131072 (L*256*256)
  ushort* w_ff1  = w_attn + 131072;             // 1048576 (L*2048*256)
  ushort* w_ff2  = w_ff1 + 1048576;             // 1048576 (L*256*2048)
  ushort* w_fc1  = w_ff2 + 1048576;             // 163840

  ushort* R16 = (ushort*)(ws + (size_t)(8u << 20));   // x16 / qkv16
  ushort* h16 = (ushort*)(ws + 8388608ull + 251658240ull);
  float*  h32 = (float*)(ws + 8388608ull + 251658240ull + 83886080ull);
  float*  t32 = (float*)(ws + 8388608ull + 251658240ull + 83886080ull + 167772160ull);
  ushort* o16 = (ushort*)(ws + 8388608ull + 251658240ull + 83886080ull + 335544320ull);

  auto cvt = [&](const float* src, ushort* dst, int n4) {
    cvt_kernel<<<(n4 + 255) / 256, 256, 0, stream>>>(src, dst, n4);
  };
  cvt(gps_w, w_gps, 32768);
  cvt(ang_w, w_ang, 32768);
  cvt(qkv_w, w_qkv, 98304);
  cvt(attn_ow, w_attn, 32768);
  cvt(ff1_w, w_ff1, 262144);
  cvt(ff2_w, w_ff2, 262144);
  cvt(fc1_w, w_fc1, 40960);
  cvt(x, R16, 20971520);   // x16 lives in R during embed

  // embed: relu(gps)->t32 (fp32); ang GEMM epilogue selects and writes h32+h16
  gemm_bt<EPI_F32_RELU><<<dim3(2, 1280), 256, 0, stream>>>(
      R16, w_gps, gps_b, t32, N_TOK, 512, 256, nullptr, nullptr, nullptr);
  gemm_bt<EPI_SELECT><<<dim3(2, 1280), 256, 0, stream>>>(
      R16, w_ang, ang_b, h32, N_TOK, 512, 256, t32, stype, h16);

  for (int l = 0; l < 2; l++) {
    gemm_bt<EPI_BF16><<<dim3(6, 1280), 256, 0, stream>>>(
        h16, w_qkv + l * 196608, qkv_b + l * 768, R16, N_TOK, 256, 768,
        nullptr, nullptr, nullptr);
    attn_kernel<<<4096, 256, 0, stream>>>(R16, o16);
    gemm_lnres<<<1280, 512, 0, stream>>>(o16, w_attn + l * 65536, attn_ob + l * 256,
                                         h32, h16, ln1_g + l * 256, ln1_b + l * 256, 256);
    ffn_fused<<<2560, 256, 0, stream>>>(h16, w_ff1 + l * 524288, ff1_b + l * 2048,
                                        w_ff2 + l * 524288, ff2_b + l * 256,
                                        h32, h16, ln2_g + l * 256, ln2_b + l * 256);
  }

  // head: fc1 (bf16 MFMA) -> z1 in t32; fc2+out in fp32
  gemm_bt<EPI_F32><<<dim3(1, 256), 256, 0, stream>>>(
      h16, w_fc1, fc1_b, t32, NBATCH, 1280, 128, nullptr, nullptr, nullptr);
  head2_kernel<<<8192, 256, 0, stream>>>(t32, fc2_w, fc2_b, out_w, out_b, (float*)d_out);
}

// Round 3
// 3135.241 us; speedup vs baseline: 1.0815x; 1.0815x over previous
//
#include <hip/hip_runtime.h>

// ---------------------------------------------------------------------------
// SensorClassifierDualEncoder on MI355X (gfx950) — R7
// B=32768, S=5, D=512, E=256, H=4 (DH=64), F=2048, L=2, C=5. N_TOK = B*S.
//
// R7: R6 proved occupancy is NOT the lever (24->30% occ, same 841us; all
// pipes <25%). Theory: per-k-step W1/W2 fragment loads (L2 ~300-600cy) are
// serially exposed; VGPR_Count=84 shows the compiler held almost nothing in
// flight, and the setprio fences likely blocked load hoisting. ffn_fused:
//  * setprio removed.
//  * P1: batch-issue ALL 16 W1 frags/chunk, then 8 pure LDS+MFMA k-steps.
//  * P2: batch-issue ALL 16 W2 frags BEFORE the barrier pair (latency hides
//    under smid phase), then 4 pure k-steps.
//  * b1 bias pair preloaded at top of P1.
//  * launch_bounds(256,2): ~190 VGPR peak, ILP over TLP.
// ---------------------------------------------------------------------------

#define N_TOK 163840
#define NBATCH 32768

typedef __attribute__((ext_vector_type(8))) short bfrag;   // 8 bf16 (4 VGPRs)
typedef __attribute__((ext_vector_type(4))) float f32x4;

__device__ __forceinline__ float bf2f(ushort u) {
  return __builtin_bit_cast(float, (uint)u << 16);
}
__device__ __forceinline__ ushort f2bf(float f) {
  uint u = __builtin_bit_cast(uint, f);
  return (ushort)((u + 0x7FFFu + ((u >> 16) & 1u)) >> 16);   // RNE
}

// --------------------------- fp32 -> bf16 cast -----------------------------
__global__ __launch_bounds__(256) void cvt_kernel(const float* __restrict__ in,
                                                  ushort* __restrict__ out, int n4) {
  int i = blockIdx.x * 256 + threadIdx.x;
  if (i >= n4) return;
  float4 v = ((const float4*)in)[i];
  ushort4 o;
  o.x = f2bf(v.x); o.y = f2bf(v.y); o.z = f2bf(v.z); o.w = f2bf(v.w);
  ((ushort4*)out)[i] = o;
}

// --------------------------- pipelined MFMA GEMM ---------------------------
// C[M,O] = A[M,K] * W[O,K]^T + bias. block 256 = 4 waves, tile 128x128.
// LDS [128][32], XOR-chunk swizzle; reg-prefetch pipeline.
enum { EPI_F32 = 0, EPI_F32_RELU = 1, EPI_BF16 = 2, EPI_BF16_RELU = 3, EPI_SELECT = 4 };

template <int EPI>
__global__ __launch_bounds__(256) void gemm_bt(const ushort* __restrict__ A,
                                               const ushort* __restrict__ W,
                                               const float* __restrict__ bias,
                                               void* __restrict__ outp,
                                               int M, int K, int O,
                                               const float* __restrict__ gbuf,
                                               const int* __restrict__ stype,
                                               ushort* __restrict__ h16out) {
  __shared__ ushort As[128][32];
  __shared__ ushort Bs[128][32];
  const int tid = threadIdx.x;
  const int wave = tid >> 6, lane = tid & 63;
  const int bm = blockIdx.y, bn = blockIdx.x;
  const int wm = (wave & 1) << 6, wn = (wave >> 1) << 6;
  const int srow = tid >> 2;                               // 0..63 (+64)
  const int sq   = tid & 3;                                // k-chunk 0..3
  const int sc   = ((sq ^ ((srow >> 2) & 3))) << 3;        // swizzled chunk
  const int scol = sq << 3;                                // global k offset

  const ushort* Abase = A + (size_t)(bm * 128 + srow) * K + scol;
  const ushort* Wbase = W + (size_t)(bn * 128 + srow) * K + scol;

  f32x4 acc[4][4];
#pragma unroll
  for (int i = 0; i < 4; i++)
#pragma unroll
    for (int j = 0; j < 4; j++) acc[i][j] = {0.f, 0.f, 0.f, 0.f};

  const int fr = lane & 15;                                // fragment row
  const int fq = lane >> 4;                                // k-quad
  const int rc = (fq ^ ((fr >> 2) & 3)) << 3;              // swizzled read chunk

  uint4 a0 = *(const uint4*)(Abase);
  uint4 a1 = *(const uint4*)(Abase + (size_t)64 * K);
  uint4 b0 = *(const uint4*)(Wbase);
  uint4 b1 = *(const uint4*)(Wbase + (size_t)64 * K);

  for (int k0 = 0; k0 < K; k0 += 32) {
    *(uint4*)&As[srow][sc]      = a0;
    *(uint4*)&As[srow + 64][sc] = a1;
    *(uint4*)&Bs[srow][sc]      = b0;
    *(uint4*)&Bs[srow + 64][sc] = b1;
    __syncthreads();
    if (k0 + 32 < K) {                  // prefetch next k-step (hidden by MFMA)
      a0 = *(const uint4*)(Abase + k0 + 32);
      a1 = *(const uint4*)(Abase + k0 + 32 + (size_t)64 * K);
      b0 = *(const uint4*)(Wbase + k0 + 32);
      b1 = *(const uint4*)(Wbase + k0 + 32 + (size_t)64 * K);
    }
    bfrag af[4], bf_[4];
#pragma unroll
    for (int i = 0; i < 4; i++) af[i] = *(const bfrag*)&As[wm + i * 16 + fr][rc];
#pragma unroll
    for (int j = 0; j < 4; j++) bf_[j] = *(const bfrag*)&Bs[wn + j * 16 + fr][rc];
#pragma unroll
    for (int i = 0; i < 4; i++)
#pragma unroll
      for (int j = 0; j < 4; j++)
        acc[i][j] = __builtin_amdgcn_mfma_f32_16x16x32_bf16(af[i], bf_[j], acc[i][j], 0, 0, 0);
    __syncthreads();
  }

  // epilogue: C/D layout col=lane&15, row=(lane>>4)*4+r
  const int cr = fq << 2;
  const int cc = fr;
#pragma unroll
  for (int j = 0; j < 4; j++) {
    const int col = bn * 128 + wn + j * 16 + cc;
    const float bv = bias[col];
#pragma unroll
    for (int i = 0; i < 4; i++) {
      const int row = bm * 128 + wm + i * 16 + cr;
#pragma unroll
      for (int r = 0; r < 4; r++) {
        float v = acc[i][j][r] + bv;
        const size_t idx = (size_t)(row + r) * O + col;
        if (EPI != EPI_F32 && EPI != EPI_BF16) v = fmaxf(v, 0.f);
        if (EPI == EPI_SELECT) {
          if (stype[row + r] == 0) v = gbuf[idx];   // gps branch precomputed
          ((float*)outp)[idx] = v;
          h16out[idx] = f2bf(v);
        } else if (EPI == EPI_F32 || EPI == EPI_F32_RELU) {
          ((float*)outp)[idx] = v;
        } else {
          ((ushort*)outp)[idx] = f2bf(v);
        }
      }
    }
  }
}

// ---------- pipelined GEMM (O=256) + residual + LayerNorm ------------------
// tile 128 rows x 256 cols, 512 thr = 8 waves, wave 64x64. Swizzled LDS.
__global__ __launch_bounds__(512) void gemm_lnres(const ushort* __restrict__ A,
                                                  const ushort* __restrict__ W,
                                                  const float* __restrict__ bias,
                                                  float* __restrict__ h32,
                                                  ushort* __restrict__ h16,
                                                  const float* __restrict__ g,
                                                  const float* __restrict__ b,
                                                  int K) {
  __shared__ ushort As[128][32];
  __shared__ ushort Bs[256][32];
  __shared__ float2 s_part[128][4];
  __shared__ float2 s_mr[128];
  const int tid = threadIdx.x;
  const int wave = tid >> 6, lane = tid & 63;
  const int bm = blockIdx.x;
  const int wm = (wave & 1) << 6, wn = (wave >> 1) << 6;

  const int srow = tid >> 2;                               // 0..127
  const int sq   = tid & 3;
  const int sc   = ((sq ^ ((srow >> 2) & 3))) << 3;
  const int scol = sq << 3;
  const ushort* Ag = A + (size_t)(bm * 128 + srow) * K + scol;
  const ushort* Wg = W + (size_t)srow * K + scol;

  f32x4 acc[4][4];
#pragma unroll
  for (int i = 0; i < 4; i++)
#pragma unroll
    for (int j = 0; j < 4; j++) acc[i][j] = {0.f, 0.f, 0.f, 0.f};

  const int fr = lane & 15;
  const int fq = lane >> 4;
  const int rc = (fq ^ ((fr >> 2) & 3)) << 3;

  uint4 a0 = *(const uint4*)(Ag);
  uint4 b0 = *(const uint4*)(Wg);
  uint4 b1 = *(const uint4*)(Wg + (size_t)128 * K);

  for (int k0 = 0; k0 < K; k0 += 32) {
    *(uint4*)&As[srow][sc]       = a0;
    *(uint4*)&Bs[srow][sc]       = b0;
    *(uint4*)&Bs[srow + 128][sc] = b1;
    __syncthreads();
    if (k0 + 32 < K) {
      a0 = *(const uint4*)(Ag + k0 + 32);
      b0 = *(const uint4*)(Wg + k0 + 32);
      b1 = *(const uint4*)(Wg + k0 + 32 + (size_t)128 * K);
    }
    bfrag af[4], bf_[4];
#pragma unroll
    for (int i = 0; i < 4; i++) af[i] = *(const bfrag*)&As[wm + i * 16 + fr][rc];
#pragma unroll
    for (int j = 0; j < 4; j++) bf_[j] = *(const bfrag*)&Bs[wn + j * 16 + fr][rc];
#pragma unroll
    for (int i = 0; i < 4; i++)
#pragma unroll
      for (int j = 0; j < 4; j++)
        acc[i][j] = __builtin_amdgcn_mfma_f32_16x16x32_bf16(af[i], bf_[j], acc[i][j], 0, 0, 0);
    __syncthreads();
  }

  const int cr = fq << 2;
  const int cc = fr;
#pragma unroll
  for (int i = 0; i < 4; i++) {
#pragma unroll
    for (int r = 0; r < 4; r++) {
      const int row = wm + i * 16 + cr + r;
      const size_t grow = (size_t)(bm * 128 + row) * 256;
      float s = 0.f, sq2 = 0.f;
#pragma unroll
      for (int j = 0; j < 4; j++) {
        const int col = wn + j * 16 + cc;
        float u = acc[i][j][r] + bias[col] + h32[grow + col];
        acc[i][j][r] = u;
        s += u; sq2 += u * u;
      }
#pragma unroll
      for (int o = 1; o < 16; o <<= 1) { s += __shfl_xor(s, o); sq2 += __shfl_xor(sq2, o); }
      if ((lane & 15) == 0) s_part[row][wave >> 1] = {s, sq2};
    }
  }
  __syncthreads();
  if (tid < 128) {
    float2 p0 = s_part[tid][0], p1 = s_part[tid][1], p2 = s_part[tid][2], p3 = s_part[tid][3];
    float S = p0.x + p1.x + p2.x + p3.x;
    float SQ = p0.y + p1.y + p2.y + p3.y;
    float mean = S * 0.00390625f;
    float var = SQ * 0.00390625f - mean * mean;
    s_mr[tid] = {mean, rsqrtf(var + 1e-5f)};
  }
  __syncthreads();
#pragma unroll
  for (int i = 0; i < 4; i++) {
#pragma unroll
    for (int r = 0; r < 4; r++) {
      const int row = wm + i * 16 + cr + r;
      const float2 mr = s_mr[row];
      const size_t grow = (size_t)(bm * 128 + row) * 256;
#pragma unroll
      for (int j = 0; j < 4; j++) {
        const int col = wn + j * 16 + cc;
        float y = (acc[i][j][r] - mr.x) * mr.y * g[col] + b[col];
        h32[grow + col] = y;
        h16[grow + col] = f2bf(y);
      }
    }
  }
}

// --------------------- fused FFN: ff1+ReLU+ff2+res+LN ----------------------
// R7: block = 256 thr (4 waves), 64 tokens, LDS 53.8KB. Deep-ILP variant:
// per chunk, ALL W1 frags batch-issued before P1's 8 pure k-steps; ALL W2
// frags batch-issued before the barrier pair (latency hides under smid
// phase). No setprio. launch_bounds(256,2) gives the VGPR headroom (~190).
__global__ __launch_bounds__(256, 2) void ffn_fused(const ushort* __restrict__ h16in,
                                                    const ushort* __restrict__ W1,
                                                    const float* __restrict__ b1,
                                                    const ushort* __restrict__ W2,
                                                    const float* __restrict__ b2,
                                                    float* __restrict__ h32,
                                                    ushort* __restrict__ h16out,
                                                    const float* __restrict__ g,
                                                    const float* __restrict__ bb) {
  __shared__ ushort sh[64][264];      // h: stride 132 dw == 4 mod 32 (2-way max)
  __shared__ ushort smid[64][136];    // mid chunk: stride 68 dw == 4 mod 32
  __shared__ float2 s_part[64][4];
  __shared__ float2 s_mr[64];
  const int tid = threadIdx.x;
  const int wave = tid >> 6, lane = tid & 63;
  const size_t tok0 = (size_t)blockIdx.x * 64;

  // stage h: 4 threads/row, 64 ushorts each
  {
    const int r = tid >> 2, c0 = (tid & 3) << 6;
    const ushort* src = h16in + (tok0 + r) * 256 + c0;
#pragma unroll
    for (int u = 0; u < 8; u++)
      *(uint4*)&sh[r][c0 + u * 8] = *(const uint4*)(src + u * 8);
  }

  const int fr = lane & 15;           // fragment row
  const int fq = lane >> 4;           // k-quad
  const int cr = fq << 2;             // C-layout row offset
  const int cc = fr;                  // C-layout col
  const int mq = wave << 5;           // P1 mid-col base (32 per wave)
  const int oq = wave << 6;           // P2 out-col base (64 per wave)

  // per-lane W base pointers
  const ushort* w1p = W1 + (size_t)(mq + fr) * 256 + fq * 8;   // +j*4096 +c*32768 +k*32
  const ushort* w2p = W2 + (size_t)(oq + fr) * 2048 + fq * 8;  // +j*32768 +c*128 +k*32

  f32x4 acc2[4][4];
#pragma unroll
  for (int i = 0; i < 4; i++)
#pragma unroll
    for (int j = 0; j < 4; j++) acc2[i][j] = {0.f, 0.f, 0.f, 0.f};

  __syncthreads();                    // sh staged

  for (int c = 0; c < 16; c++) {
    const size_t c1 = (size_t)c * 32768;    // W1 chunk offset (128 rows * 256)

    // ---- batch-issue ALL W1 frags for this chunk (16 loads in flight) ----
    bfrag w1f[8][2];
#pragma unroll
    for (int k = 0; k < 8; k++) {
      w1f[k][0] = *(const bfrag*)(w1p + c1 + k * 32);
      w1f[k][1] = *(const bfrag*)(w1p + c1 + 16 * 256 + k * 32);
    }
    // bias pair for this chunk (hidden under P1 compute)
    const float bv0 = b1[c * 128 + mq + cc];
    const float bv1 = b1[c * 128 + mq + 16 + cc];

    // ---- P1: mid = relu(h * W1[c]^T + b1) ; 64 tok x 32 mid per wave ----
    f32x4 acc1[4][2];
#pragma unroll
    for (int i = 0; i < 4; i++)
#pragma unroll
      for (int j = 0; j < 2; j++) acc1[i][j] = {0.f, 0.f, 0.f, 0.f};
#pragma unroll
    for (int k = 0; k < 8; k++) {
      const int ko = k * 32 + fq * 8;
      bfrag af[4];
#pragma unroll
      for (int i = 0; i < 4; i++) af[i] = *(const bfrag*)&sh[i * 16 + fr][ko];
#pragma unroll
      for (int i = 0; i < 4; i++)
#pragma unroll
        for (int j = 0; j < 2; j++)
          acc1[i][j] = __builtin_amdgcn_mfma_f32_16x16x32_bf16(af[i], w1f[k][j], acc1[i][j], 0, 0, 0);
    }

    // ---- batch-issue ALL W2 frags; latency hides under smid phase ----
    bfrag w2f[4][4];
#pragma unroll
    for (int k = 0; k < 4; k++)
#pragma unroll
      for (int j = 0; j < 4; j++)
        w2f[k][j] = *(const bfrag*)(w2p + (size_t)j * 32768 + c * 128 + k * 32);

    __syncthreads();   // prev P2 done reading smid
#pragma unroll
    for (int i = 0; i < 4; i++)
#pragma unroll
      for (int r = 0; r < 4; r++) {
        float v0 = fmaxf(acc1[i][0][r] + bv0, 0.f);
        float v1 = fmaxf(acc1[i][1][r] + bv1, 0.f);
        smid[i * 16 + cr + r][mq + cc]      = f2bf(v0);
        smid[i * 16 + cr + r][mq + 16 + cc] = f2bf(v1);
      }
    __syncthreads();   // smid ready

    // ---- P2: acc2 += mid * W2[:,c]^T ; 64 tok x 64 out per wave ----
#pragma unroll
    for (int k = 0; k < 4; k++) {
      const int ko = k * 32 + fq * 8;
      bfrag af[4];
#pragma unroll
      for (int i = 0; i < 4; i++) af[i] = *(const bfrag*)&smid[i * 16 + fr][ko];
#pragma unroll
      for (int i = 0; i < 4; i++)
#pragma unroll
        for (int j = 0; j < 4; j++)
          acc2[i][j] = __builtin_amdgcn_mfma_f32_16x16x32_bf16(af[i], w2f[k][j], acc2[i][j], 0, 0, 0);
    }
  }

  // ---- epilogue: u = acc2 + b2 + h32 ; LN -> h32, h16 ----
#pragma unroll
  for (int i = 0; i < 4; i++) {
#pragma unroll
    for (int r = 0; r < 4; r++) {
      const int row = i * 16 + cr + r;
      const size_t grow = (tok0 + row) * 256;
      float s = 0.f, sq2 = 0.f;
#pragma unroll
      for (int j = 0; j < 4; j++) {
        const int col = oq + j * 16 + cc;
        float u = acc2[i][j][r] + b2[col] + h32[grow + col];
        acc2[i][j][r] = u;
        s += u; sq2 += u * u;
      }
#pragma unroll
      for (int o = 1; o < 16; o <<= 1) { s += __shfl_xor(s, o); sq2 += __shfl_xor(sq2, o); }
      if ((lane & 15) == 0) s_part[row][wave] = {s, sq2};
    }
  }
  __syncthreads();
  if (tid < 64) {
    float2 p0 = s_part[tid][0], p1 = s_part[tid][1], p2 = s_part[tid][2], p3 = s_part[tid][3];
    float S = p0.x + p1.x + p2.x + p3.x;
    float SQ = p0.y + p1.y + p2.y + p3.y;
    float mean = S * 0.00390625f;
    float var = SQ * 0.00390625f - mean * mean;
    s_mr[tid] = {mean, rsqrtf(var + 1e-5f)};
  }
  __syncthreads();
#pragma unroll
  for (int i = 0; i < 4; i++) {
#pragma unroll
    for (int r = 0; r < 4; r++) {
      const int row = i * 16 + cr + r;
      const float2 mr = s_mr[row];
      const size_t grow = (tok0 + row) * 256;
#pragma unroll
      for (int j = 0; j < 4; j++) {
        const int col = oq + j * 16 + cc;
        float y = (acc2[i][j][r] - mr.x) * mr.y * g[col] + bb[col];
        h32[grow + col] = y;
        h16out[grow + col] = f2bf(y);
      }
    }
  }
}

// --------------------------- attention (S=5) -------------------------------
__global__ __launch_bounds__(256) void attn_kernel(const ushort* __restrict__ qkv,
                                                   ushort* __restrict__ o16) {
  __shared__ ushort s_qkv[8 * 5 * 768];   // 61440 B
  __shared__ float s_att[8 * 4 * 25];
  const int tid = threadIdx.x;
  const size_t gbase = (size_t)blockIdx.x * (8 * 5 * 768);
#pragma unroll
  for (int t = 0; t < 15; t++) {
    int i = tid + t * 256;
    *(uint4*)&s_qkv[i * 8] = *(const uint4*)(qkv + gbase + (size_t)i * 8);
  }
  __syncthreads();
  for (int idx = tid; idx < 800; idx += 256) {
    int b = idx / 100, r = idx - b * 100;
    int h = r / 25, ij = r - h * 25;
    int i = ij / 5, j = ij - i * 5;
    const ushort* qp = &s_qkv[(b * 5 + i) * 768 + h * 64];
    const ushort* kp = &s_qkv[(b * 5 + j) * 768 + 256 + h * 64];
    float s = 0.f;
#pragma unroll
    for (int d = 0; d < 64; d += 2) {
      uint qw = *(const uint*)&qp[d];
      uint kw = *(const uint*)&kp[d];
      s += bf2f((ushort)(qw & 0xffffu)) * bf2f((ushort)(kw & 0xffffu));
      s += bf2f((ushort)(qw >> 16)) * bf2f((ushort)(kw >> 16));
    }
    s_att[idx] = s * 0.125f;   // 1/sqrt(64)
  }
  __syncthreads();
  if (tid < 160) {
    float* sp = &s_att[tid * 5];
    float m = fmaxf(fmaxf(fmaxf(sp[0], sp[1]), fmaxf(sp[2], sp[3])), sp[4]);
    float e0 = __expf(sp[0] - m), e1 = __expf(sp[1] - m), e2 = __expf(sp[2] - m);
    float e3 = __expf(sp[3] - m), e4 = __expf(sp[4] - m);
    float inv = 1.f / (e0 + e1 + e2 + e3 + e4);
    sp[0] = e0 * inv; sp[1] = e1 * inv; sp[2] = e2 * inv; sp[3] = e3 * inv; sp[4] = e4 * inv;
  }
  __syncthreads();
  const size_t obase = (size_t)blockIdx.x * (8 * 5 * 256);
#pragma unroll
  for (int t = 0; t < 40; t++) {
    int idx = t * 256 + tid;
    int d = idx & 63;
    int rest = idx >> 6;
    int h = rest & 3; rest >>= 2;
    int i = rest % 5, b = rest / 5;
    const float* ap = &s_att[(b * 4 + h) * 25 + i * 5];
    const ushort* vp = &s_qkv[(b * 5) * 768 + 512 + h * 64 + d];
    float o = 0.f;
#pragma unroll
    for (int j = 0; j < 5; j++) o += ap[j] * bf2f(vp[j * 768]);
    o16[obase + (size_t)((b * 5 + i) * 256 + h * 64 + d)] = f2bf(o);
  }
}

// --------------------------- head: fc2 + out (fp32) ------------------------
__global__ __launch_bounds__(256) void head2_kernel(const float* __restrict__ z1,
                                                    const float* __restrict__ fc2w,
                                                    const float* __restrict__ fc2b,
                                                    const float* __restrict__ outw,
                                                    const float* __restrict__ outb,
                                                    float* __restrict__ out) {
  __shared__ float s_z2[4][64];
  const int wave = threadIdx.x >> 6, lane = threadIdx.x & 63;
  const int b = blockIdx.x * 4 + wave;
  const float* z = z1 + (size_t)b * 128;
  float acc = fc2b[lane];
#pragma unroll 8
  for (int k = 0; k < 128; k++) acc += z[k] * fc2w[lane * 128 + k];
  s_z2[wave][lane] = acc;
  __syncthreads();
  if (lane < 5) {
    const float* zz = s_z2[wave];
    float o = outb[lane];
#pragma unroll 8
    for (int k = 0; k < 64; k++) o += zz[k] * outw[lane * 64 + k];
    out[(size_t)b * 5 + lane] = o;
  }
}

// ---------------------------------------------------------------------------
extern "C" void kernel_launch(void* const* d_in, const int* in_sizes, int n_in,
                              void* d_out, int out_size, void* d_ws, size_t ws_size,
                              hipStream_t stream) {
  const float* x       = (const float*)d_in[0];
  const int*   stype   = (const int*)d_in[1];
  const float* gps_w   = (const float*)d_in[2];
  const float* gps_b   = (const float*)d_in[3];
  const float* ang_w   = (const float*)d_in[4];
  const float* ang_b   = (const float*)d_in[5];
  const float* qkv_w   = (const float*)d_in[6];
  const float* qkv_b   = (const float*)d_in[7];
  const float* attn_ow = (const float*)d_in[8];
  const float* attn_ob = (const float*)d_in[9];
  const float* ln1_g   = (const float*)d_in[10];
  const float* ln1_b   = (const float*)d_in[11];
  const float* ff1_w   = (const float*)d_in[12];
  const float* ff1_b   = (const float*)d_in[13];
  const float* ff2_w   = (const float*)d_in[14];
  const float* ff2_b   = (const float*)d_in[15];
  const float* ln2_g   = (const float*)d_in[16];
  const float* ln2_b   = (const float*)d_in[17];
  const float* fc1_w   = (const float*)d_in[18];
  const float* fc1_b   = (const float*)d_in[19];
  const float* fc2_w   = (const float*)d_in[20];
  const float* fc2_b   = (const float*)d_in[21];
  const float* out_w   = (const float*)d_in[22];
  const float* out_b   = (const float*)d_in[23];

  char* ws = (char*)d_ws;
  const size_t NEED = 763363328ull;
  if (ws_size < NEED) return;

  // bf16 weight pool
  ushort* w_gps  = (ushort*)ws;                 // 131072
  ushort* w_ang  = w_gps + 131072;
  ushort* w_qkv  = w_ang + 131072;              // 393216 (L*768*256)
  ushort* w_attn = w_qkv + 393216;              // 131072 (L*256*256)
  ushort* w_ff1  = w_attn + 131072;             // 1048576 (L*2048*256)
  ushort* w_ff2  = w_ff1 + 1048576;             // 1048576 (L*256*2048)
  ushort* w_fc1  = w_ff2 + 1048576;             // 163840

  ushort* R16 = (ushort*)(ws + (size_t)(8u << 20));   // x16 / qkv16
  ushort* h16 = (ushort*)(ws + 8388608ull + 251658240ull);
  float*  h32 = (float*)(ws + 8388608ull + 251658240ull + 83886080ull);
  float*  t32 = (float*)(ws + 8388608ull + 251658240ull + 83886080ull + 167772160ull);
  ushort* o16 = (ushort*)(ws + 8388608ull + 251658240ull + 83886080ull + 335544320ull);

  auto cvt = [&](const float* src, ushort* dst, int n4) {
    cvt_kernel<<<(n4 + 255) / 256, 256, 0, stream>>>(src, dst, n4);
  };
  cvt(gps_w, w_gps, 32768);
  cvt(ang_w, w_ang, 32768);
  cvt(qkv_w, w_qkv, 98304);
  cvt(attn_ow, w_attn, 32768);
  cvt(ff1_w, w_ff1, 262144);
  cvt(ff2_w, w_ff2, 262144);
  cvt(fc1_w, w_fc1, 40960);
  cvt(x, R16, 20971520);   // x16 lives in R during embed

  // embed: relu(gps)->t32 (fp32); ang GEMM epilogue selects and writes h32+h16
  gemm_bt<EPI_F32_RELU><<<dim3(2, 1280), 256, 0, stream>>>(
      R16, w_gps, gps_b, t32, N_TOK, 512, 256, nullptr, nullptr, nullptr);
  gemm_bt<EPI_SELECT><<<dim3(2, 1280), 256, 0, stream>>>(
      R16, w_ang, ang_b, h32, N_TOK, 512, 256, t32, stype, h16);

  for (int l = 0; l < 2; l++) {
    gemm_bt<EPI_BF16><<<dim3(6, 1280), 256, 0, stream>>>(
        h16, w_qkv + l * 196608, qkv_b + l * 768, R16, N_TOK, 256, 768,
        nullptr, nullptr, nullptr);
    attn_kernel<<<4096, 256, 0, stream>>>(R16, o16);
    gemm_lnres<<<1280, 512, 0, stream>>>(o16, w_attn + l * 65536, attn_ob + l * 256,
                                         h32, h16, ln1_g + l * 256, ln1_b + l * 256, 256);
    ffn_fused<<<2560, 256, 0, stream>>>(h16, w_ff1 + l * 524288, ff1_b + l * 2048,
                                        w_ff2 + l * 524288, ff2_b + l * 256,
                                        h32, h16, ln2_g + l * 256, ln2_b + l * 256);
  }

  // head: fc1 (bf16 MFMA) -> z1 in t32; fc2+out in fp32
  gemm_bt<EPI_F32><<<dim3(1, 256), 256, 0, stream>>>(
      h16, w_fc1, fc1_b, t32, NBATCH, 1280, 128, nullptr, nullptr, nullptr);
  head2_kernel<<<8192, 256, 0, stream>>>(t32, fc2_w, fc2_b, out_w, out_b, (float*)d_out);
}